// Round 1
// baseline (1538.630 us; speedup 1.0000x reference)
//
#include <hip/hip_runtime.h>

#define FEAT 32
#define EMB 32
#define HID 128
#define OUT_DIM 256
#define NGRAPHS 64

// ---------- helpers ----------
__device__ __forceinline__ unsigned enc_f32(float f) {
  unsigned u = __float_as_uint(f);
  return (u & 0x80000000u) ? ~u : (u | 0x80000000u);
}
__device__ __forceinline__ float dec_f32(unsigned e) {
  unsigned u = (e & 0x80000000u) ? (e ^ 0x80000000u) : ~e;
  return __uint_as_float(u);
}

// ---------- CSR build ----------
__global__ void hist_k(const int* __restrict__ dst, int* __restrict__ indeg, int E) {
  int e = blockIdx.x * blockDim.x + threadIdx.x;
  if (e < E) atomicAdd(&indeg[dst[e]], 1);
}

__global__ void dinv_k(const int* __restrict__ indeg, float* __restrict__ dinv, int N) {
  int i = blockIdx.x * blockDim.x + threadIdx.x;
  if (i < N) dinv[i] = rsqrtf((float)indeg[i] + 1.0f);  // +1 self loop
}

__global__ __launch_bounds__(1024) void scan_k(const int* __restrict__ indeg,
                                               int* __restrict__ row_start,
                                               int* __restrict__ cursor, int N) {
  __shared__ int wsum[16];
  __shared__ int carry_s;
  if (threadIdx.x == 0) carry_s = 0;
  __syncthreads();
  const int lane = threadIdx.x & 63;
  const int wid = threadIdx.x >> 6;
  for (int base = 0; base < N; base += 1024) {
    int i = base + (int)threadIdx.x;
    int val = (i < N) ? indeg[i] : 0;
    int x = val;
#pragma unroll
    for (int off = 1; off < 64; off <<= 1) {
      int y = __shfl_up(x, off, 64);
      if (lane >= off) x += y;
    }
    if (lane == 63) wsum[wid] = x;
    __syncthreads();
    if (wid == 0) {
      int s = (lane < 16) ? wsum[lane] : 0;
#pragma unroll
      for (int off = 1; off < 16; off <<= 1) {
        int y = __shfl_up(s, off, 64);
        if (lane >= off) s += y;
      }
      if (lane < 16) wsum[lane] = s;
    }
    __syncthreads();
    int excl = carry_s + x - val + ((wid > 0) ? wsum[wid - 1] : 0);
    if (i < N) { row_start[i] = excl; cursor[i] = excl; }
    __syncthreads();
    if (threadIdx.x == 0) carry_s += wsum[15];
    __syncthreads();
  }
  if (threadIdx.x == 0) row_start[N] = carry_s;
}

__global__ void fill_k(const int* __restrict__ src, const int* __restrict__ dst,
                       const float* __restrict__ dinv, int* __restrict__ cursor,
                       int* __restrict__ csr_src, int* __restrict__ csr_dst,
                       float* __restrict__ csr_norm, int E) {
  int e = blockIdx.x * blockDim.x + threadIdx.x;
  if (e >= E) return;
  int d = dst[e], s = src[e];
  int p = atomicAdd(&cursor[d], 1);
  csr_src[p] = s;
  csr_dst[p] = d;
  csr_norm[p] = dinv[s] * dinv[d];
}

// ---------- feature assembly ----------
__global__ void xcat_k(const float* __restrict__ nodes, const int* __restrict__ cats,
                       const float* __restrict__ emb, float* __restrict__ xcat, int N) {
  int t = blockIdx.x * blockDim.x + threadIdx.x;  // N*16 float4 slots
  int i = t >> 4, q = t & 15;
  if (i >= N) return;
  float4 v;
  if (q < 8) v = ((const float4*)nodes)[i * 8 + q];
  else       v = ((const float4*)emb)[cats[i] * 8 + (q - 8)];
  ((float4*)xcat)[i * 16 + q] = v;
}

// ---------- generic f32 GEMM: C[M x 128] = A[M x K] @ B[K x 128] ----------
__global__ __launch_bounds__(256) void gemm_k(const float* __restrict__ A,
                                              const float* __restrict__ B,
                                              float* __restrict__ C, int M, int K) {
  __shared__ float As[64][16];
  __shared__ float Bs[16][128];
  const int t = threadIdx.x;
  const int ty = t >> 5, tx = t & 31;
  const int row0 = blockIdx.x * 64;
  float acc[8][4];
#pragma unroll
  for (int r = 0; r < 8; r++)
#pragma unroll
    for (int q = 0; q < 4; q++) acc[r][q] = 0.f;

  for (int k0 = 0; k0 < K; k0 += 16) {
    {  // stage A: 64x16
      int r = t >> 2, kq = (t & 3) * 4;
      int gr = row0 + r;
      float4 av = make_float4(0.f, 0.f, 0.f, 0.f);
      if (gr < M) av = *(const float4*)&A[(size_t)gr * K + k0 + kq];
      *(float4*)&As[r][kq] = av;
    }
    {  // stage B: 16x128
      int kk = t >> 4, c = (t & 15) * 8;
      *(float4*)&Bs[kk][c]     = *(const float4*)&B[(size_t)(k0 + kk) * 128 + c];
      *(float4*)&Bs[kk][c + 4] = *(const float4*)&B[(size_t)(k0 + kk) * 128 + c + 4];
    }
    __syncthreads();
#pragma unroll
    for (int k = 0; k < 16; k += 4) {
      float bv[4][4];
#pragma unroll
      for (int kk = 0; kk < 4; kk++) *(float4*)&bv[kk][0] = *(float4*)&Bs[k + kk][tx * 4];
#pragma unroll
      for (int rr = 0; rr < 8; rr++) {
        float a[4];
        *(float4*)a = *(float4*)&As[ty * 8 + rr][k];
#pragma unroll
        for (int kk = 0; kk < 4; kk++)
#pragma unroll
          for (int q = 0; q < 4; q++)
            acc[rr][q] = fmaf(a[kk], bv[kk][q], acc[rr][q]);
      }
    }
    __syncthreads();
  }
#pragma unroll
  for (int rr = 0; rr < 8; rr++) {
    int gr = row0 + ty * 8 + rr;
    if (gr < M) {
      float4 o = make_float4(acc[rr][0], acc[rr][1], acc[rr][2], acc[rr][3]);
      *(float4*)&C[(size_t)gr * 128 + tx * 4] = o;
    }
  }
}

// ---------- GCN aggregate: out = relu(sum_{in-edges} h[src]*norm + h[i]/deg + b) ----------
__global__ __launch_bounds__(256) void gcn_agg_k(const float* __restrict__ h,
                                                 const int* __restrict__ csr_src,
                                                 const float* __restrict__ csr_norm,
                                                 const int* __restrict__ row_start,
                                                 const float* __restrict__ dinv,
                                                 const float* __restrict__ bias,
                                                 float* __restrict__ out, int N) {
  int w = (blockIdx.x * blockDim.x + threadIdx.x) >> 6;
  int lane = threadIdx.x & 63;
  if (w >= N) return;
  const int i = w;
  float di = dinv[i];
  float sn = di * di;
  const float2* h2 = (const float2*)h;
  float2 self = h2[(size_t)i * 64 + lane];
  float a0 = self.x * sn, a1 = self.y * sn;
  int s0 = row_start[i], s1 = row_start[i + 1];
  for (int p = s0; p < s1; p++) {
    int s = csr_src[p];
    float wgt = csr_norm[p];
    float2 hv = h2[(size_t)s * 64 + lane];
    a0 = fmaf(hv.x, wgt, a0);
    a1 = fmaf(hv.y, wgt, a1);
  }
  float2 bv = ((const float2*)bias)[lane];
  float2 o;
  o.x = fmaxf(a0 + bv.x, 0.f);
  o.y = fmaxf(a1 + bv.y, 0.f);
  ((float2*)out)[(size_t)i * 64 + lane] = o;
}

// ---------- Wd = We1_top - We1_bot ----------
__global__ void wd_k(const float* __restrict__ We1, float* __restrict__ Wd) {
  int t = blockIdx.x * blockDim.x + threadIdx.x;  // 128*128
  Wd[t] = We1[t] - We1[16384 + t];
}

// ---------- EdgeConv: per-edge relu(u[dst]+v[src]+be1) @ We2 + be2, segment-max to dst ----------
__global__ __launch_bounds__(256) void edgeconv_k(const float* __restrict__ U,
                                                  const float* __restrict__ V,
                                                  const int* __restrict__ csr_src,
                                                  const int* __restrict__ csr_dst,
                                                  const float* __restrict__ be1,
                                                  const float* __restrict__ We2,
                                                  const float* __restrict__ be2,
                                                  unsigned* __restrict__ agg, int E) {
  __shared__ float Hs[64][128];
  __shared__ float Bs[32][128];
  const int t = threadIdx.x;
  const int ty = t >> 5, tx = t & 31;
  const int tb = blockIdx.x * 64;

  // stage H tile (fused relu(u[dst]+v[src]+be1))
  {
    const int k4 = (t & 31) * 4;
    const int rbase = t >> 5;
    float4 b1v = *(const float4*)&be1[k4];
#pragma unroll
    for (int it = 0; it < 8; ++it) {
      int r = rbase + it * 8;
      int p = tb + r;
      float4 hv = make_float4(0.f, 0.f, 0.f, 0.f);
      if (p < E) {
        int i = csr_dst[p], j = csr_src[p];
        float4 uu = *(const float4*)&U[(size_t)i * 128 + k4];
        float4 vv = *(const float4*)&V[(size_t)j * 128 + k4];
        hv.x = fmaxf(uu.x + vv.x + b1v.x, 0.f);
        hv.y = fmaxf(uu.y + vv.y + b1v.y, 0.f);
        hv.z = fmaxf(uu.z + vv.z + b1v.z, 0.f);
        hv.w = fmaxf(uu.w + vv.w + b1v.w, 0.f);
      }
      *(float4*)&Hs[r][k4] = hv;
    }
  }

  float acc[8][4];
#pragma unroll
  for (int r = 0; r < 8; r++)
#pragma unroll
    for (int q = 0; q < 4; q++) acc[r][q] = 0.f;

  for (int k0 = 0; k0 < 128; k0 += 32) {
    __syncthreads();  // Hs ready (first iter) / Bs consumers done (later iters)
    {                 // stage We2 chunk: 32x128
      int kk = t >> 3, c0 = (t & 7) * 16;
      const float* srcp = &We2[(size_t)(k0 + kk) * 128 + c0];
      *(float4*)&Bs[kk][c0]      = *(const float4*)&srcp[0];
      *(float4*)&Bs[kk][c0 + 4]  = *(const float4*)&srcp[4];
      *(float4*)&Bs[kk][c0 + 8]  = *(const float4*)&srcp[8];
      *(float4*)&Bs[kk][c0 + 12] = *(const float4*)&srcp[12];
    }
    __syncthreads();
#pragma unroll
    for (int k = 0; k < 32; k += 4) {
      float bv[4][4];
#pragma unroll
      for (int kk = 0; kk < 4; kk++) *(float4*)&bv[kk][0] = *(float4*)&Bs[k + kk][tx * 4];
#pragma unroll
      for (int rr = 0; rr < 8; rr++) {
        float a[4];
        *(float4*)a = *(float4*)&Hs[ty * 8 + rr][k0 + k];
#pragma unroll
        for (int kk = 0; kk < 4; kk++)
#pragma unroll
          for (int q = 0; q < 4; q++)
            acc[rr][q] = fmaf(a[kk], bv[kk][q], acc[rr][q]);
      }
    }
  }

  // epilogue: run-length max over CSR-contiguous dst, then atomic-max
  float4 b2v = *(const float4*)&be2[tx * 4];
  int curd = -1;
  float rm0 = 0.f, rm1 = 0.f, rm2 = 0.f, rm3 = 0.f;
#pragma unroll
  for (int rr = 0; rr < 8; rr++) {
    int p = tb + ty * 8 + rr;
    if (p >= E) break;
    int d = csr_dst[p];
    float m0 = acc[rr][0] + b2v.x;
    float m1 = acc[rr][1] + b2v.y;
    float m2 = acc[rr][2] + b2v.z;
    float m3 = acc[rr][3] + b2v.w;
    if (d != curd) {
      if (curd >= 0) {
        atomicMax(&agg[(size_t)curd * 128 + tx * 4 + 0], enc_f32(rm0));
        atomicMax(&agg[(size_t)curd * 128 + tx * 4 + 1], enc_f32(rm1));
        atomicMax(&agg[(size_t)curd * 128 + tx * 4 + 2], enc_f32(rm2));
        atomicMax(&agg[(size_t)curd * 128 + tx * 4 + 3], enc_f32(rm3));
      }
      curd = d; rm0 = m0; rm1 = m1; rm2 = m2; rm3 = m3;
    } else {
      rm0 = fmaxf(rm0, m0); rm1 = fmaxf(rm1, m1);
      rm2 = fmaxf(rm2, m2); rm3 = fmaxf(rm3, m3);
    }
  }
  if (curd >= 0) {
    atomicMax(&agg[(size_t)curd * 128 + tx * 4 + 0], enc_f32(rm0));
    atomicMax(&agg[(size_t)curd * 128 + tx * 4 + 1], enc_f32(rm1));
    atomicMax(&agg[(size_t)curd * 128 + tx * 4 + 2], enc_f32(rm2));
    atomicMax(&agg[(size_t)curd * 128 + tx * 4 + 3], enc_f32(rm3));
  }
}

// ---------- decode max-agg + relu ----------
__global__ void decode_k(const unsigned* __restrict__ agg, float* __restrict__ x, int total) {
  int t = blockIdx.x * blockDim.x + threadIdx.x;
  if (t >= total) return;
  unsigned e = agg[t];
  float v = (e == 0u) ? 0.f : dec_f32(e);
  x[t] = fmaxf(v, 0.f);
}

// ---------- pooling (max + sum + count) ----------
__global__ void pool_k(const float* __restrict__ x, const int* __restrict__ batch,
                       unsigned* __restrict__ gmax, float* __restrict__ gsum,
                       float* __restrict__ cnt, int N) {
  int w = (blockIdx.x * blockDim.x + threadIdx.x) >> 6;
  int lane = threadIdx.x & 63;
  if (w >= N) return;
  int g = batch[w];
  float2 v = ((const float2*)x)[(size_t)w * 64 + lane];
  atomicMax(&gmax[g * 128 + lane * 2 + 0], enc_f32(v.x));
  atomicMax(&gmax[g * 128 + lane * 2 + 1], enc_f32(v.y));
  atomicAdd(&gsum[g * 128 + lane * 2 + 0], v.x);
  atomicAdd(&gsum[g * 128 + lane * 2 + 1], v.y);
  if (lane == 0) atomicAdd(&cnt[g], 1.f);
}

__global__ void g0_k(const unsigned* __restrict__ gmax, const float* __restrict__ gsum,
                     const float* __restrict__ cnt, float* __restrict__ g0) {
  int t = blockIdx.x * blockDim.x + threadIdx.x;  // 64*256
  int g = t >> 8, c = t & 255;
  float o;
  if (c < 128) {
    unsigned e = gmax[g * 128 + c];
    o = (e == 0u) ? 0.f : dec_f32(e);
  } else {
    o = gsum[g * 128 + (c - 128)] / fmaxf(cnt[g], 1.f);
  }
  g0[t] = o;
}

// ---------- head FC (relu) ----------
__global__ __launch_bounds__(256) void fc_k(const float* __restrict__ X,
                                            const float* __restrict__ W,
                                            const float* __restrict__ b,
                                            float* __restrict__ Y, int K, int N) {
  __shared__ float xs[256];
  int g = blockIdx.x, c = threadIdx.x;
  for (int k = c; k < K; k += blockDim.x) xs[k] = X[g * K + k];
  __syncthreads();
  float acc = b[c];
  for (int k = 0; k < K; k++) acc = fmaf(xs[k], W[(size_t)k * N + c], acc);
  Y[g * N + c] = fmaxf(acc, 0.f);
}

// ---------- launch ----------
extern "C" void kernel_launch(void* const* d_in, const int* in_sizes, int n_in,
                              void* d_out, int out_size, void* d_ws, size_t ws_size,
                              hipStream_t stream) {
  const float* nodes  = (const float*)d_in[0];
  const int*   cats   = (const int*)d_in[1];
  const int*   eidx   = (const int*)d_in[2];
  const int*   batch  = (const int*)d_in[3];
  const float* emb    = (const float*)d_in[4];
  const float* W1 = (const float*)d_in[5];
  const float* b1 = (const float*)d_in[6];
  const float* W2 = (const float*)d_in[7];
  const float* b2 = (const float*)d_in[8];
  const float* W3 = (const float*)d_in[9];
  const float* b3 = (const float*)d_in[10];
  const float* We1 = (const float*)d_in[11];
  const float* be1 = (const float*)d_in[12];
  const float* We2 = (const float*)d_in[13];
  const float* be2 = (const float*)d_in[14];
  const float* Wf1 = (const float*)d_in[15];
  const float* bf1 = (const float*)d_in[16];
  const float* Wf2 = (const float*)d_in[17];
  const float* bf2 = (const float*)d_in[18];
  float* out = (float*)d_out;

  const int N = in_sizes[0] / FEAT;
  const int E = in_sizes[2] / 2;
  const int* src = eidx;
  const int* dst = eidx + E;

  // workspace carve-up
  char* w = (char*)d_ws;
  auto alloc = [&](size_t bytes) -> void* {
    void* p = (void*)w;
    w += (bytes + 255) & ~(size_t)255;
    return p;
  };
  float*    xcat  = (float*)alloc((size_t)N * 64 * 4);
  float*    bufA  = (float*)alloc((size_t)N * 128 * 4);
  float*    bufB  = (float*)alloc((size_t)N * 128 * 4);
  float*    bufC  = (float*)alloc((size_t)N * 128 * 4);
  unsigned* aggD  = (unsigned*)alloc((size_t)N * 128 * 4);
  int*   indeg    = (int*)alloc((size_t)N * 4);
  int*   rowst    = (int*)alloc((size_t)(N + 1) * 4);
  int*   cursor   = (int*)alloc((size_t)N * 4);
  float* dinv     = (float*)alloc((size_t)N * 4);
  int*   csr_src  = (int*)alloc((size_t)E * 4);
  int*   csr_dst  = (int*)alloc((size_t)E * 4);
  float* csr_norm = (float*)alloc((size_t)E * 4);
  float* Wd       = (float*)alloc(128 * 128 * 4);
  float* g0buf    = (float*)alloc(NGRAPHS * 256 * 4);
  float* g1buf    = (float*)alloc(NGRAPHS * 256 * 4);
  unsigned* gmax  = (unsigned*)alloc(NGRAPHS * 128 * 4);
  float* gsum     = (float*)alloc(NGRAPHS * 128 * 4);
  float* cnt      = (float*)alloc(NGRAPHS * 4);
  if ((size_t)(w - (char*)d_ws) > ws_size) return;  // insufficient workspace

  // zero-init
  hipMemsetAsync(indeg, 0, (size_t)N * 4, stream);
  hipMemsetAsync(aggD, 0, (size_t)N * 128 * 4, stream);
  hipMemsetAsync(gmax, 0, NGRAPHS * 128 * 4, stream);
  hipMemsetAsync(gsum, 0, NGRAPHS * 128 * 4, stream);
  hipMemsetAsync(cnt, 0, NGRAPHS * 4, stream);

  const int TB = 256;
  int gE = (E + TB - 1) / TB;
  int gN = (N + TB - 1) / TB;

  // CSR + norms
  hist_k<<<gE, TB, 0, stream>>>(dst, indeg, E);
  dinv_k<<<gN, TB, 0, stream>>>(indeg, dinv, N);
  scan_k<<<1, 1024, 0, stream>>>(indeg, rowst, cursor, N);
  fill_k<<<gE, TB, 0, stream>>>(src, dst, dinv, cursor, csr_src, csr_dst, csr_norm, E);

  // features
  xcat_k<<<(N * 16 + TB - 1) / TB, TB, 0, stream>>>(nodes, cats, emb, xcat, N);

  int gemmGrid = (N + 63) / 64;
  int waveGrid = (N * 64 + TB - 1) / TB;  // one wave per node

  // GCN layer 1: xcat(64) -> bufA -> bufB
  gemm_k<<<gemmGrid, TB, 0, stream>>>(xcat, W1, bufA, N, 64);
  gcn_agg_k<<<waveGrid, TB, 0, stream>>>(bufA, csr_src, csr_norm, rowst, dinv, b1, bufB, N);
  // GCN layer 2: bufB -> bufA -> bufC
  gemm_k<<<gemmGrid, TB, 0, stream>>>(bufB, W2, bufA, N, 128);
  gcn_agg_k<<<waveGrid, TB, 0, stream>>>(bufA, csr_src, csr_norm, rowst, dinv, b2, bufC, N);
  // GCN layer 3: bufC -> bufA -> bufB (x3)
  gemm_k<<<gemmGrid, TB, 0, stream>>>(bufC, W3, bufA, N, 128);
  gcn_agg_k<<<waveGrid, TB, 0, stream>>>(bufA, csr_src, csr_norm, rowst, dinv, b3, bufB, N);

  // EdgeConv precompute: u = x3@(top-bot) -> bufA ; v = x3@bot -> bufC
  wd_k<<<(128 * 128) / TB, TB, 0, stream>>>(We1, Wd);
  gemm_k<<<gemmGrid, TB, 0, stream>>>(bufB, Wd, bufA, N, 128);
  gemm_k<<<gemmGrid, TB, 0, stream>>>(bufB, We1 + 128 * 128, bufC, N, 128);

  // EdgeConv main + segment max
  edgeconv_k<<<(E + 63) / 64, TB, 0, stream>>>(bufA, bufC, csr_src, csr_dst, be1, We2, be2,
                                               aggD, E);
  decode_k<<<(N * 128 + TB - 1) / TB, TB, 0, stream>>>(aggD, bufB, N * 128);

  // pooling + head
  pool_k<<<waveGrid, TB, 0, stream>>>(bufB, batch, gmax, gsum, cnt, N);
  g0_k<<<(NGRAPHS * 256) / TB, TB, 0, stream>>>(gmax, gsum, cnt, g0buf);
  fc_k<<<NGRAPHS, 256, 0, stream>>>(g0buf, Wf1, bf1, g1buf, 256, 256);
  fc_k<<<NGRAPHS, 256, 0, stream>>>(g1buf, Wf2, bf2, out, 256, 256);
}

// Round 2
// 1324.199 us; speedup vs baseline: 1.1619x; 1.1619x over previous
//
#include <hip/hip_runtime.h>

#define FEAT 32
#define EMB 32
#define HID 128
#define NGRAPHS 64

typedef short short8 __attribute__((ext_vector_type(8)));
typedef float f32x4 __attribute__((ext_vector_type(4)));

union B8 { uint4 q; unsigned u[4]; short8 v; };

// round-to-nearest-even bf16, returned as f32 bits with low16 zeroed
__device__ __forceinline__ unsigned bf16_rne_bits(float f) {
  unsigned u = __float_as_uint(f);
  unsigned r = u + 0x7FFFu + ((u >> 16) & 1u);
  return r & 0xFFFF0000u;
}
// split a,b (f32) into packed bf16 hi-pair and lo-pair (elem0 low16, elem1 high16)
__device__ __forceinline__ void split2(float a, float b, unsigned& hp, unsigned& lp) {
  unsigned ha = bf16_rne_bits(a), hb = bf16_rne_bits(b);
  float la = a - __uint_as_float(ha), lb = b - __uint_as_float(hb);
  unsigned laa = bf16_rne_bits(la), lbb = bf16_rne_bits(lb);
  hp = (ha >> 16) | (hb & 0xFFFF0000u);
  lp = (laa >> 16) | (lbb & 0xFFFF0000u);
}

// ---------- CSR build ----------
__global__ void hist_k(const int* __restrict__ dst, int* __restrict__ indeg, int E) {
  int e = blockIdx.x * blockDim.x + threadIdx.x;
  if (e < E) atomicAdd(&indeg[dst[e]], 1);
}

__global__ void dinv_k(const int* __restrict__ indeg, float* __restrict__ dinv, int N) {
  int i = blockIdx.x * blockDim.x + threadIdx.x;
  if (i < N) dinv[i] = rsqrtf((float)indeg[i] + 1.0f);  // +1 self loop
}

__global__ __launch_bounds__(1024) void scan_k(const int* __restrict__ indeg,
                                               int* __restrict__ row_start,
                                               int* __restrict__ cursor, int N) {
  __shared__ int wsum[16];
  __shared__ int carry_s;
  if (threadIdx.x == 0) carry_s = 0;
  __syncthreads();
  const int lane = threadIdx.x & 63;
  const int wid = threadIdx.x >> 6;
  for (int base = 0; base < N; base += 1024) {
    int i = base + (int)threadIdx.x;
    int val = (i < N) ? indeg[i] : 0;
    int x = val;
#pragma unroll
    for (int off = 1; off < 64; off <<= 1) {
      int y = __shfl_up(x, off, 64);
      if (lane >= off) x += y;
    }
    if (lane == 63) wsum[wid] = x;
    __syncthreads();
    if (wid == 0) {
      int s = (lane < 16) ? wsum[lane] : 0;
#pragma unroll
      for (int off = 1; off < 16; off <<= 1) {
        int y = __shfl_up(s, off, 64);
        if (lane >= off) s += y;
      }
      if (lane < 16) wsum[lane] = s;
    }
    __syncthreads();
    int excl = carry_s + x - val + ((wid > 0) ? wsum[wid - 1] : 0);
    if (i < N) { row_start[i] = excl; cursor[i] = excl; }
    __syncthreads();
    if (threadIdx.x == 0) carry_s += wsum[15];
    __syncthreads();
  }
  if (threadIdx.x == 0) row_start[N] = carry_s;
}

__global__ void fill_k(const int* __restrict__ src, const int* __restrict__ dst,
                       const float* __restrict__ dinv, int* __restrict__ cursor,
                       int* __restrict__ csr_src, int* __restrict__ csr_dst,
                       float* __restrict__ csr_norm, int E) {
  int e = blockIdx.x * blockDim.x + threadIdx.x;
  if (e >= E) return;
  int d = dst[e], s = src[e];
  int p = atomicAdd(&cursor[d], 1);
  csr_src[p] = s;
  csr_dst[p] = d;
  csr_norm[p] = dinv[s] * dinv[d];
}

// ---------- weight packing into MFMA-fragment layout (hi then lo) ----------
// out[((kt*4+ks)*128 + c)*8 + j] = bf16(W[kt*32+ks*8+j][c]); lo at +K*128
__global__ void pack_k(const float* __restrict__ WA, const float* __restrict__ WB,
                       unsigned short* __restrict__ out, int K) {
  int t = blockIdx.x * blockDim.x + threadIdx.x;
  if (t >= K * 128) return;
  int k = t >> 7, c = t & 127;
  float v = WA[k * 128 + c];
  if (WB) v -= WB[k * 128 + c];
  unsigned hb = bf16_rne_bits(v);
  float lo = v - __uint_as_float(hb);
  unsigned lb = bf16_rne_bits(lo);
  int kt = k >> 5, ks = (k >> 3) & 3, j = k & 7;
  int idx = ((kt * 4 + ks) * 128 + c) * 8 + j;
  out[idx] = (unsigned short)(hb >> 16);
  out[K * 128 + idx] = (unsigned short)(lb >> 16);
}

// ---------- feature assembly: split concat(nodes, emb[cat]) to bf16 hi/lo ----------
__global__ void xcat_split_k(const float* __restrict__ nodes, const int* __restrict__ cats,
                             const float* __restrict__ emb, unsigned* __restrict__ xh,
                             unsigned* __restrict__ xl, int N) {
  int t = blockIdx.x * blockDim.x + threadIdx.x;  // N*32, 2 channels each
  if (t >= N * 32) return;
  int i = t >> 5, p = t & 31;
  float2 v = (p < 16) ? ((const float2*)nodes)[(size_t)i * 16 + p]
                      : ((const float2*)emb)[(size_t)cats[i] * 16 + (p - 16)];
  unsigned hp, lp;
  split2(v.x, v.y, hp, lp);
  xh[(size_t)i * 32 + p] = hp;
  xl[(size_t)i * 32 + p] = lp;
}

// ---------- split-bf16 MFMA GEMM: C[M x 128] = A @ B ; A row-major K, B packed ----------
__global__ __launch_bounds__(256) void gemm_mfma(const unsigned short* __restrict__ Ah,
                                                 const unsigned short* __restrict__ Al,
                                                 const unsigned short* __restrict__ Bp,
                                                 float* __restrict__ C, int M, int K) {
  __shared__ uint4 Blds[4096];  // 64KB max (K=128); K=64 uses 2048
  const int nq = K * 32;        // uint4 count (hi+lo)
  for (int i = threadIdx.x; i < nq; i += 256) Blds[i] = ((const uint4*)Bp)[i];
  __syncthreads();
  const int w = threadIdx.x >> 6, lane = threadIdx.x & 63;
  const int ks = lane >> 4, fr = lane & 15;
  const int rb0 = blockIdx.x * 128 + w * 32;
  const int loBase = K * 16;  // uint4 offset of lo half
  f32x4 acc[2][8];
#pragma unroll
  for (int m = 0; m < 2; ++m)
#pragma unroll
    for (int ct = 0; ct < 8; ++ct) acc[m][ct] = (f32x4)0.f;

  const int nkt = K >> 5;
  for (int kt = 0; kt < nkt; ++kt) {
    B8 ah[2], al[2];
#pragma unroll
    for (int m = 0; m < 2; ++m) {
      size_t off = (size_t)(rb0 + m * 16 + fr) * K + kt * 32 + ks * 8;
      ah[m].q = *(const uint4*)(Ah + off);
      al[m].q = *(const uint4*)(Al + off);
    }
#pragma unroll
    for (int ct = 0; ct < 8; ++ct) {
      int bidx = (kt * 4 + ks) * 128 + ct * 16 + fr;
      B8 bh, bl;
      bh.q = Blds[bidx];
      bl.q = Blds[bidx + loBase];
#pragma unroll
      for (int m = 0; m < 2; ++m) {
        acc[m][ct] = __builtin_amdgcn_mfma_f32_16x16x32_bf16(ah[m].v, bh.v, acc[m][ct], 0, 0, 0);
        acc[m][ct] = __builtin_amdgcn_mfma_f32_16x16x32_bf16(ah[m].v, bl.v, acc[m][ct], 0, 0, 0);
        acc[m][ct] = __builtin_amdgcn_mfma_f32_16x16x32_bf16(al[m].v, bh.v, acc[m][ct], 0, 0, 0);
      }
    }
  }
#pragma unroll
  for (int m = 0; m < 2; ++m)
#pragma unroll
    for (int ct = 0; ct < 8; ++ct) {
      int col = ct * 16 + fr;
#pragma unroll
      for (int r = 0; r < 4; ++r) {
        int row = rb0 + m * 16 + ks * 4 + r;
        if (row < M) C[(size_t)row * 128 + col] = acc[m][ct][r];
      }
    }
}

// ---------- GCN aggregate + relu + split to bf16 hi/lo ----------
__global__ __launch_bounds__(256) void gcn_agg_split_k(
    const float* __restrict__ h, const int* __restrict__ csr_src,
    const float* __restrict__ csr_norm, const int* __restrict__ row_start,
    const float* __restrict__ dinv, const float* __restrict__ bias,
    unsigned* __restrict__ out_hi, unsigned* __restrict__ out_lo, int N) {
  int i = (blockIdx.x * blockDim.x + threadIdx.x) >> 6;
  int lane = threadIdx.x & 63;
  if (i >= N) return;
  float di = dinv[i];
  float sn = di * di;
  const float2* h2 = (const float2*)h;
  float2 self = h2[(size_t)i * 64 + lane];
  float a0 = self.x * sn, a1 = self.y * sn;
  int s0 = row_start[i], s1 = row_start[i + 1];
  for (int p = s0; p < s1; p++) {
    int s = csr_src[p];
    float wgt = csr_norm[p];
    float2 hv = h2[(size_t)s * 64 + lane];
    a0 = fmaf(hv.x, wgt, a0);
    a1 = fmaf(hv.y, wgt, a1);
  }
  float2 bv = ((const float2*)bias)[lane];
  a0 = fmaxf(a0 + bv.x, 0.f);
  a1 = fmaxf(a1 + bv.y, 0.f);
  unsigned hp, lp;
  split2(a0, a1, hp, lp);
  out_hi[(size_t)i * 64 + lane] = hp;
  out_lo[(size_t)i * 64 + lane] = lp;
}

// ---------- EdgeConv: MFMA split-bf16, H computed on the fly, run-length max epilogue ----------
__global__ __launch_bounds__(256) void edgeconv_mfma(
    const float* __restrict__ U, const float* __restrict__ V,
    const int* __restrict__ csr_src, const int* __restrict__ csr_dst,
    const float* __restrict__ be1, const unsigned short* __restrict__ We2p,
    const float* __restrict__ be2, unsigned* __restrict__ agg, int E, int ntiles) {
  __shared__ uint4 Blds[4096];  // We2 hi (2048) + lo (2048)
  for (int i = threadIdx.x; i < 4096; i += 256) Blds[i] = ((const uint4*)We2p)[i];
  __syncthreads();
  const int w = threadIdx.x >> 6, lane = threadIdx.x & 63;
  const int ks = lane >> 4, fr = lane & 15;
  float b2[8];
#pragma unroll
  for (int ct = 0; ct < 8; ++ct) b2[ct] = be2[ct * 16 + fr];

  for (int tile = blockIdx.x; tile < ntiles; tile += gridDim.x) {
    const int eb = tile * 128 + w * 32;
    // A-side edge ids (row-permuted so C rows land on 8 consecutive edges/lane)
    int dA[2], sA[2];
#pragma unroll
    for (int m = 0; m < 2; ++m) {
      int el = ((fr >> 2) << 3) + (m << 2) + (fr & 3);
      int e = eb + el;
      int ee = (e < E) ? e : 0;
      dA[m] = csr_dst[ee];
      sA[m] = csr_src[ee];
    }
    f32x4 acc[2][8];
#pragma unroll
    for (int m = 0; m < 2; ++m)
#pragma unroll
      for (int ct = 0; ct < 8; ++ct) acc[m][ct] = (f32x4)0.f;

    for (int kt = 0; kt < 4; ++kt) {
      const int k0 = kt * 32 + ks * 8;
      float4 bb0 = *(const float4*)&be1[k0];
      float4 bb1 = *(const float4*)&be1[k0 + 4];
      B8 ah[2], al[2];
#pragma unroll
      for (int m = 0; m < 2; ++m) {
        const float4* up = (const float4*)&U[(size_t)dA[m] * 128 + k0];
        const float4* vp = (const float4*)&V[(size_t)sA[m] * 128 + k0];
        float4 u0 = up[0], u1 = up[1], v0 = vp[0], v1 = vp[1];
        float s0 = fmaxf(u0.x + v0.x + bb0.x, 0.f);
        float s1 = fmaxf(u0.y + v0.y + bb0.y, 0.f);
        float s2 = fmaxf(u0.z + v0.z + bb0.z, 0.f);
        float s3 = fmaxf(u0.w + v0.w + bb0.w, 0.f);
        float s4 = fmaxf(u1.x + v1.x + bb1.x, 0.f);
        float s5 = fmaxf(u1.y + v1.y + bb1.y, 0.f);
        float s6 = fmaxf(u1.z + v1.z + bb1.z, 0.f);
        float s7 = fmaxf(u1.w + v1.w + bb1.w, 0.f);
        split2(s0, s1, ah[m].u[0], al[m].u[0]);
        split2(s2, s3, ah[m].u[1], al[m].u[1]);
        split2(s4, s5, ah[m].u[2], al[m].u[2]);
        split2(s6, s7, ah[m].u[3], al[m].u[3]);
      }
#pragma unroll
      for (int ct = 0; ct < 8; ++ct) {
        int bidx = (kt * 4 + ks) * 128 + ct * 16 + fr;
        B8 bh, bl;
        bh.q = Blds[bidx];
        bl.q = Blds[bidx + 2048];
#pragma unroll
        for (int m = 0; m < 2; ++m) {
          acc[m][ct] = __builtin_amdgcn_mfma_f32_16x16x32_bf16(ah[m].v, bh.v, acc[m][ct], 0, 0, 0);
          acc[m][ct] = __builtin_amdgcn_mfma_f32_16x16x32_bf16(ah[m].v, bl.v, acc[m][ct], 0, 0, 0);
          acc[m][ct] = __builtin_amdgcn_mfma_f32_16x16x32_bf16(al[m].v, bh.v, acc[m][ct], 0, 0, 0);
        }
      }
    }
    // epilogue: lane's 8 consecutive edges = (m,r) regs; run-length max, relu-first atomicMax
    const int ebase = eb + ks * 8;
    int prev = -1;
    float runv[8];
#pragma unroll
    for (int j = 0; j < 8; ++j) {
      int e = ebase + j;
      if (e < E) {
        int d = csr_dst[e];
        const int m = j >> 2, r = j & 3;
        if (d != prev) {
          if (prev >= 0) {
#pragma unroll
            for (int ct = 0; ct < 8; ++ct)
              atomicMax(&agg[(size_t)prev * 128 + ct * 16 + fr], __float_as_uint(runv[ct]));
          }
          prev = d;
#pragma unroll
          for (int ct = 0; ct < 8; ++ct) runv[ct] = fmaxf(acc[m][ct][r] + b2[ct], 0.f);
        } else {
#pragma unroll
          for (int ct = 0; ct < 8; ++ct)
            runv[ct] = fmaxf(runv[ct], fmaxf(acc[m][ct][r] + b2[ct], 0.f));
        }
      }
    }
    if (prev >= 0) {
#pragma unroll
      for (int ct = 0; ct < 8; ++ct)
        atomicMax(&agg[(size_t)prev * 128 + ct * 16 + fr], __float_as_uint(runv[ct]));
    }
  }
}

// ---------- pooling (max + sum + count); x = relu'd agg (f32, >=0) ----------
__global__ void pool_k(const float* __restrict__ x, const int* __restrict__ batch,
                       unsigned* __restrict__ gmax, float* __restrict__ gsum,
                       float* __restrict__ cnt, int N) {
  int i = (blockIdx.x * blockDim.x + threadIdx.x) >> 6;
  int lane = threadIdx.x & 63;
  if (i >= N) return;
  int g = batch[i];
  float2 v = ((const float2*)x)[(size_t)i * 64 + lane];
  atomicMax(&gmax[g * 128 + lane * 2 + 0], __float_as_uint(v.x));
  atomicMax(&gmax[g * 128 + lane * 2 + 1], __float_as_uint(v.y));
  atomicAdd(&gsum[g * 128 + lane * 2 + 0], v.x);
  atomicAdd(&gsum[g * 128 + lane * 2 + 1], v.y);
  if (lane == 0) atomicAdd(&cnt[g], 1.f);
}

__global__ void g0_k(const unsigned* __restrict__ gmax, const float* __restrict__ gsum,
                     const float* __restrict__ cnt, float* __restrict__ g0) {
  int t = blockIdx.x * blockDim.x + threadIdx.x;  // 64*256
  int g = t >> 8, c = t & 255;
  float o;
  if (c < 128) o = __uint_as_float(gmax[g * 128 + c]);
  else o = gsum[g * 128 + (c - 128)] / fmaxf(cnt[g], 1.f);
  g0[t] = o;
}

// ---------- head FC (relu) ----------
__global__ __launch_bounds__(256) void fc_k(const float* __restrict__ X,
                                            const float* __restrict__ W,
                                            const float* __restrict__ b,
                                            float* __restrict__ Y, int K, int N) {
  __shared__ float xs[256];
  int g = blockIdx.x, c = threadIdx.x;
  for (int k = c; k < K; k += blockDim.x) xs[k] = X[g * K + k];
  __syncthreads();
  float acc = b[c];
  for (int k = 0; k < K; k++) acc = fmaf(xs[k], W[(size_t)k * N + c], acc);
  Y[g * N + c] = fmaxf(acc, 0.f);
}

// ---------- launch ----------
extern "C" void kernel_launch(void* const* d_in, const int* in_sizes, int n_in,
                              void* d_out, int out_size, void* d_ws, size_t ws_size,
                              hipStream_t stream) {
  const float* nodes = (const float*)d_in[0];
  const int* cats = (const int*)d_in[1];
  const int* eidx = (const int*)d_in[2];
  const int* batch = (const int*)d_in[3];
  const float* emb = (const float*)d_in[4];
  const float* W1 = (const float*)d_in[5];
  const float* b1 = (const float*)d_in[6];
  const float* W2 = (const float*)d_in[7];
  const float* b2 = (const float*)d_in[8];
  const float* W3 = (const float*)d_in[9];
  const float* b3 = (const float*)d_in[10];
  const float* We1 = (const float*)d_in[11];
  const float* be1 = (const float*)d_in[12];
  const float* We2 = (const float*)d_in[13];
  const float* be2 = (const float*)d_in[14];
  const float* Wf1 = (const float*)d_in[15];
  const float* bf1 = (const float*)d_in[16];
  const float* Wf2 = (const float*)d_in[17];
  const float* bf2 = (const float*)d_in[18];
  float* out = (float*)d_out;

  const int N = in_sizes[0] / FEAT;
  const int E = in_sizes[2] / 2;
  const int Npad = ((N + 127) / 128) * 128;
  const int* src = eidx;
  const int* dst = eidx + E;

  char* w = (char*)d_ws;
  auto alloc = [&](size_t bytes) -> void* {
    void* p = (void*)w;
    w += (bytes + 255) & ~(size_t)255;
    return p;
  };
  unsigned* xh = (unsigned*)alloc((size_t)Npad * 32 * 4);   // [Npad x 64] bf16 pairs
  unsigned* xl = (unsigned*)alloc((size_t)Npad * 32 * 4);
  unsigned* ahb = (unsigned*)alloc((size_t)Npad * 64 * 4);  // [Npad x 128] bf16 pairs
  unsigned* alb = (unsigned*)alloc((size_t)Npad * 64 * 4);
  float* bufF = (float*)alloc((size_t)Npad * 128 * 4);      // gemm out / U
  float* bufV = (float*)alloc((size_t)Npad * 128 * 4);
  unsigned* agg = (unsigned*)alloc((size_t)N * 128 * 4);
  int* indeg = (int*)alloc((size_t)N * 4);
  int* rowst = (int*)alloc((size_t)(N + 1) * 4);
  int* cursor = (int*)alloc((size_t)N * 4);
  float* dinv = (float*)alloc((size_t)N * 4);
  int* csr_src = (int*)alloc((size_t)E * 4);
  int* csr_dst = (int*)alloc((size_t)E * 4);
  float* csr_norm = (float*)alloc((size_t)E * 4);
  unsigned short* W1p = (unsigned short*)alloc(2 * 64 * 128 * 2);
  unsigned short* W2p = (unsigned short*)alloc(2 * 128 * 128 * 2);
  unsigned short* W3p = (unsigned short*)alloc(2 * 128 * 128 * 2);
  unsigned short* Wdp = (unsigned short*)alloc(2 * 128 * 128 * 2);
  unsigned short* Wvp = (unsigned short*)alloc(2 * 128 * 128 * 2);
  unsigned short* We2p = (unsigned short*)alloc(2 * 128 * 128 * 2);
  float* g0buf = (float*)alloc(NGRAPHS * 256 * 4);
  float* g1buf = (float*)alloc(NGRAPHS * 256 * 4);
  unsigned* gmax = (unsigned*)alloc(NGRAPHS * 128 * 4);
  float* gsum = (float*)alloc(NGRAPHS * 128 * 4);
  float* cnt = (float*)alloc(NGRAPHS * 4);
  if ((size_t)(w - (char*)d_ws) > ws_size) return;

  hipMemsetAsync(indeg, 0, (size_t)N * 4, stream);
  hipMemsetAsync(agg, 0, (size_t)N * 128 * 4, stream);
  hipMemsetAsync(gmax, 0, NGRAPHS * 128 * 4, stream);
  hipMemsetAsync(gsum, 0, NGRAPHS * 128 * 4, stream);
  hipMemsetAsync(cnt, 0, NGRAPHS * 4, stream);

  const int TB = 256;
  int gE = (E + TB - 1) / TB;
  int gN = (N + TB - 1) / TB;

  hist_k<<<gE, TB, 0, stream>>>(dst, indeg, E);
  dinv_k<<<gN, TB, 0, stream>>>(indeg, dinv, N);
  scan_k<<<1, 1024, 0, stream>>>(indeg, rowst, cursor, N);
  fill_k<<<gE, TB, 0, stream>>>(src, dst, dinv, cursor, csr_src, csr_dst, csr_norm, E);

  xcat_split_k<<<(N * 32 + TB - 1) / TB, TB, 0, stream>>>(nodes, cats, emb, xh, xl, N);

  pack_k<<<32, TB, 0, stream>>>(W1, nullptr, W1p, 64);
  pack_k<<<64, TB, 0, stream>>>(W2, nullptr, W2p, 128);
  pack_k<<<64, TB, 0, stream>>>(W3, nullptr, W3p, 128);
  pack_k<<<64, TB, 0, stream>>>(We1, We1 + 128 * 128, Wdp, 128);  // top - bot
  pack_k<<<64, TB, 0, stream>>>(We1 + 128 * 128, nullptr, Wvp, 128);
  pack_k<<<64, TB, 0, stream>>>(We2, nullptr, We2p, 128);

  const int gemmGrid = Npad / 128;
  const int waveGrid = (N * 64 + TB - 1) / TB;

  gemm_mfma<<<gemmGrid, TB, 0, stream>>>((unsigned short*)xh, (unsigned short*)xl, W1p, bufF, N, 64);
  gcn_agg_split_k<<<waveGrid, TB, 0, stream>>>(bufF, csr_src, csr_norm, rowst, dinv, b1, ahb, alb, N);
  gemm_mfma<<<gemmGrid, TB, 0, stream>>>((unsigned short*)ahb, (unsigned short*)alb, W2p, bufF, N, 128);
  gcn_agg_split_k<<<waveGrid, TB, 0, stream>>>(bufF, csr_src, csr_norm, rowst, dinv, b2, ahb, alb, N);
  gemm_mfma<<<gemmGrid, TB, 0, stream>>>((unsigned short*)ahb, (unsigned short*)alb, W3p, bufF, N, 128);
  gcn_agg_split_k<<<waveGrid, TB, 0, stream>>>(bufF, csr_src, csr_norm, rowst, dinv, b3, ahb, alb, N);

  // EdgeConv precompute: U = x3 @ (We1_top - We1_bot) -> bufF ; V = x3 @ We1_bot -> bufV
  gemm_mfma<<<gemmGrid, TB, 0, stream>>>((unsigned short*)ahb, (unsigned short*)alb, Wdp, bufF, N, 128);
  gemm_mfma<<<gemmGrid, TB, 0, stream>>>((unsigned short*)ahb, (unsigned short*)alb, Wvp, bufV, N, 128);

  const int ntiles = (E + 127) / 128;
  edgeconv_mfma<<<2048, TB, 0, stream>>>(bufF, bufV, csr_src, csr_dst, be1, We2p, be2, agg, E, ntiles);

  pool_k<<<waveGrid, TB, 0, stream>>>((const float*)agg, batch, gmax, gsum, cnt, N);
  g0_k<<<NGRAPHS, TB, 0, stream>>>(gmax, gsum, cnt, g0buf);
  fc_k<<<NGRAPHS, 256, 0, stream>>>(g0buf, Wf1, bf1, g1buf, 256, 256);
  fc_k<<<NGRAPHS, 256, 0, stream>>>(g1buf, Wf2, bf2, out, 256, 256);
}

// Round 3
// 910.633 us; speedup vs baseline: 1.6896x; 1.4542x over previous
//
#include <hip/hip_runtime.h>

#define FEAT 32
#define EMB 32
#define HID 128
#define NGRAPHS 64

typedef short short8 __attribute__((ext_vector_type(8)));
typedef float f32x4 __attribute__((ext_vector_type(4)));

union B8 { uint4 q; unsigned u[4]; short8 v; };

// round-to-nearest-even bf16, returned as f32 bits with low16 zeroed
__device__ __forceinline__ unsigned bf16_rne_bits(float f) {
  unsigned u = __float_as_uint(f);
  unsigned r = u + 0x7FFFu + ((u >> 16) & 1u);
  return r & 0xFFFF0000u;
}
// split a,b (f32) into packed bf16 hi-pair and lo-pair (elem0 low16, elem1 high16)
__device__ __forceinline__ void split2(float a, float b, unsigned& hp, unsigned& lp) {
  unsigned ha = bf16_rne_bits(a), hb = bf16_rne_bits(b);
  float la = a - __uint_as_float(ha), lb = b - __uint_as_float(hb);
  unsigned laa = bf16_rne_bits(la), lbb = bf16_rne_bits(lb);
  hp = (ha >> 16) | (hb & 0xFFFF0000u);
  lp = (laa >> 16) | (lbb & 0xFFFF0000u);
}

// ---------- CSR build ----------
__global__ void hist_k(const int* __restrict__ dst, int* __restrict__ indeg, int E) {
  int e = blockIdx.x * blockDim.x + threadIdx.x;
  if (e < E) atomicAdd(&indeg[dst[e]], 1);
}

__global__ void dinv_k(const int* __restrict__ indeg, float* __restrict__ dinv, int N) {
  int i = blockIdx.x * blockDim.x + threadIdx.x;
  if (i < N) dinv[i] = rsqrtf((float)indeg[i] + 1.0f);  // +1 self loop
}

__global__ __launch_bounds__(1024) void scan_k(const int* __restrict__ indeg,
                                               int* __restrict__ row_start,
                                               int* __restrict__ cursor, int N) {
  __shared__ int wsum[16];
  __shared__ int carry_s;
  if (threadIdx.x == 0) carry_s = 0;
  __syncthreads();
  const int lane = threadIdx.x & 63;
  const int wid = threadIdx.x >> 6;
  for (int base = 0; base < N; base += 1024) {
    int i = base + (int)threadIdx.x;
    int val = (i < N) ? indeg[i] : 0;
    int x = val;
#pragma unroll
    for (int off = 1; off < 64; off <<= 1) {
      int y = __shfl_up(x, off, 64);
      if (lane >= off) x += y;
    }
    if (lane == 63) wsum[wid] = x;
    __syncthreads();
    if (wid == 0) {
      int s = (lane < 16) ? wsum[lane] : 0;
#pragma unroll
      for (int off = 1; off < 16; off <<= 1) {
        int y = __shfl_up(s, off, 64);
        if (lane >= off) s += y;
      }
      if (lane < 16) wsum[lane] = s;
    }
    __syncthreads();
    int excl = carry_s + x - val + ((wid > 0) ? wsum[wid - 1] : 0);
    if (i < N) { row_start[i] = excl; cursor[i] = excl; }
    __syncthreads();
    if (threadIdx.x == 0) carry_s += wsum[15];
    __syncthreads();
  }
  if (threadIdx.x == 0) row_start[N] = carry_s;
}

__global__ void fill_k(const int* __restrict__ src, const int* __restrict__ dst,
                       const float* __restrict__ dinv, int* __restrict__ cursor,
                       int* __restrict__ csr_src, int* __restrict__ csr_dst,
                       float* __restrict__ csr_norm, int E) {
  int e = blockIdx.x * blockDim.x + threadIdx.x;
  if (e >= E) return;
  int d = dst[e], s = src[e];
  int p = atomicAdd(&cursor[d], 1);
  csr_src[p] = s;
  csr_dst[p] = d;
  csr_norm[p] = dinv[s] * dinv[d];
}

// ---------- weight packing into MFMA-fragment layout (hi then lo) ----------
// out[((kt*4+ks)*128 + c)*8 + j] = bf16(W[kt*32+ks*8+j][c]); lo at +K*128
__global__ void pack_k(const float* __restrict__ WA, const float* __restrict__ WB,
                       unsigned short* __restrict__ out, int K) {
  int t = blockIdx.x * blockDim.x + threadIdx.x;
  if (t >= K * 128) return;
  int k = t >> 7, c = t & 127;
  float v = WA[k * 128 + c];
  if (WB) v -= WB[k * 128 + c];
  unsigned hb = bf16_rne_bits(v);
  float lo = v - __uint_as_float(hb);
  unsigned lb = bf16_rne_bits(lo);
  int kt = k >> 5, ks = (k >> 3) & 3, j = k & 7;
  int idx = ((kt * 4 + ks) * 128 + c) * 8 + j;
  out[idx] = (unsigned short)(hb >> 16);
  out[K * 128 + idx] = (unsigned short)(lb >> 16);
}

// ---------- feature assembly: split concat(nodes, emb[cat]) to bf16 hi/lo ----------
__global__ void xcat_split_k(const float* __restrict__ nodes, const int* __restrict__ cats,
                             const float* __restrict__ emb, unsigned* __restrict__ xh,
                             unsigned* __restrict__ xl, int N) {
  int t = blockIdx.x * blockDim.x + threadIdx.x;  // N*32, 2 channels each
  if (t >= N * 32) return;
  int i = t >> 5, p = t & 31;
  float2 v = (p < 16) ? ((const float2*)nodes)[(size_t)i * 16 + p]
                      : ((const float2*)emb)[(size_t)cats[i] * 16 + (p - 16)];
  unsigned hp, lp;
  split2(v.x, v.y, hp, lp);
  xh[(size_t)i * 32 + p] = hp;
  xl[(size_t)i * 32 + p] = lp;
}

// ---------- split-bf16 MFMA GEMM: C[M x 128] = A @ B ; A row-major K, B packed ----------
__global__ __launch_bounds__(256) void gemm_mfma(const unsigned short* __restrict__ Ah,
                                                 const unsigned short* __restrict__ Al,
                                                 const unsigned short* __restrict__ Bp,
                                                 float* __restrict__ C, int M, int K) {
  __shared__ uint4 Blds[4096];  // 64KB max (K=128); K=64 uses 2048
  const int nq = K * 32;        // uint4 count (hi+lo)
  for (int i = threadIdx.x; i < nq; i += 256) Blds[i] = ((const uint4*)Bp)[i];
  __syncthreads();
  const int w = threadIdx.x >> 6, lane = threadIdx.x & 63;
  const int ks = lane >> 4, fr = lane & 15;
  const int rb0 = blockIdx.x * 128 + w * 32;
  const int loBase = K * 16;  // uint4 offset of lo half
  f32x4 acc[2][8];
#pragma unroll
  for (int m = 0; m < 2; ++m)
#pragma unroll
    for (int ct = 0; ct < 8; ++ct) acc[m][ct] = (f32x4)0.f;

  const int nkt = K >> 5;
  for (int kt = 0; kt < nkt; ++kt) {
    B8 ah[2], al[2];
#pragma unroll
    for (int m = 0; m < 2; ++m) {
      size_t off = (size_t)(rb0 + m * 16 + fr) * K + kt * 32 + ks * 8;
      ah[m].q = *(const uint4*)(Ah + off);
      al[m].q = *(const uint4*)(Al + off);
    }
#pragma unroll
    for (int ct = 0; ct < 8; ++ct) {
      int bidx = (kt * 4 + ks) * 128 + ct * 16 + fr;
      B8 bh, bl;
      bh.q = Blds[bidx];
      bl.q = Blds[bidx + loBase];
#pragma unroll
      for (int m = 0; m < 2; ++m) {
        acc[m][ct] = __builtin_amdgcn_mfma_f32_16x16x32_bf16(ah[m].v, bh.v, acc[m][ct], 0, 0, 0);
        acc[m][ct] = __builtin_amdgcn_mfma_f32_16x16x32_bf16(ah[m].v, bl.v, acc[m][ct], 0, 0, 0);
        acc[m][ct] = __builtin_amdgcn_mfma_f32_16x16x32_bf16(al[m].v, bh.v, acc[m][ct], 0, 0, 0);
      }
    }
  }
#pragma unroll
  for (int m = 0; m < 2; ++m)
#pragma unroll
    for (int ct = 0; ct < 8; ++ct) {
      int col = ct * 16 + fr;
#pragma unroll
      for (int r = 0; r < 4; ++r) {
        int row = rb0 + m * 16 + ks * 4 + r;
        if (row < M) C[(size_t)row * 128 + col] = acc[m][ct][r];
      }
    }
}

// ---------- GCN aggregate + relu + split to bf16 hi/lo ----------
__global__ __launch_bounds__(256) void gcn_agg_split_k(
    const float* __restrict__ h, const int* __restrict__ csr_src,
    const float* __restrict__ csr_norm, const int* __restrict__ row_start,
    const float* __restrict__ dinv, const float* __restrict__ bias,
    unsigned* __restrict__ out_hi, unsigned* __restrict__ out_lo, int N) {
  int i = (blockIdx.x * blockDim.x + threadIdx.x) >> 6;
  int lane = threadIdx.x & 63;
  if (i >= N) return;
  float di = dinv[i];
  float sn = di * di;
  const float2* h2 = (const float2*)h;
  float2 self = h2[(size_t)i * 64 + lane];
  float a0 = self.x * sn, a1 = self.y * sn;
  int s0 = row_start[i], s1 = row_start[i + 1];
  for (int p = s0; p < s1; p++) {
    int s = csr_src[p];
    float wgt = csr_norm[p];
    float2 hv = h2[(size_t)s * 64 + lane];
    a0 = fmaf(hv.x, wgt, a0);
    a1 = fmaf(hv.y, wgt, a1);
  }
  float2 bv = ((const float2*)bias)[lane];
  a0 = fmaxf(a0 + bv.x, 0.f);
  a1 = fmaxf(a1 + bv.y, 0.f);
  unsigned hp, lp;
  split2(a0, a1, hp, lp);
  out_hi[(size_t)i * 64 + lane] = hp;
  out_lo[(size_t)i * 64 + lane] = lp;
}

// ---------- EdgeConv: MFMA split-bf16, H computed on the fly, run-length max epilogue ----------
__global__ __launch_bounds__(256) void edgeconv_mfma(
    const float* __restrict__ U, const float* __restrict__ V,
    const int* __restrict__ csr_src, const int* __restrict__ csr_dst,
    const float* __restrict__ be1, const unsigned short* __restrict__ We2p,
    const float* __restrict__ be2, unsigned* __restrict__ agg, int E, int ntiles) {
  __shared__ uint4 Blds[4096];  // We2 hi (2048) + lo (2048)
  for (int i = threadIdx.x; i < 4096; i += 256) Blds[i] = ((const uint4*)We2p)[i];
  __syncthreads();
  const int w = threadIdx.x >> 6, lane = threadIdx.x & 63;
  const int ks = lane >> 4, fr = lane & 15;
  float b2[8];
#pragma unroll
  for (int ct = 0; ct < 8; ++ct) b2[ct] = be2[ct * 16 + fr];

  for (int tile = blockIdx.x; tile < ntiles; tile += gridDim.x) {
    const int eb = tile * 128 + w * 32;
    // A-side edge ids (row-permuted so C rows land on 8 consecutive edges/lane)
    int dA[2], sA[2];
#pragma unroll
    for (int m = 0; m < 2; ++m) {
      int el = ((fr >> 2) << 3) + (m << 2) + (fr & 3);
      int e = eb + el;
      int ee = (e < E) ? e : 0;
      dA[m] = csr_dst[ee];
      sA[m] = csr_src[ee];
    }
    f32x4 acc[2][8];
#pragma unroll
    for (int m = 0; m < 2; ++m)
#pragma unroll
      for (int ct = 0; ct < 8; ++ct) acc[m][ct] = (f32x4)0.f;

    for (int kt = 0; kt < 4; ++kt) {
      const int k0 = kt * 32 + ks * 8;
      float4 bb0 = *(const float4*)&be1[k0];
      float4 bb1 = *(const float4*)&be1[k0 + 4];
      B8 ah[2], al[2];
#pragma unroll
      for (int m = 0; m < 2; ++m) {
        const float4* up = (const float4*)&U[(size_t)dA[m] * 128 + k0];
        const float4* vp = (const float4*)&V[(size_t)sA[m] * 128 + k0];
        float4 u0 = up[0], u1 = up[1], v0 = vp[0], v1 = vp[1];
        float s0 = fmaxf(u0.x + v0.x + bb0.x, 0.f);
        float s1 = fmaxf(u0.y + v0.y + bb0.y, 0.f);
        float s2 = fmaxf(u0.z + v0.z + bb0.z, 0.f);
        float s3 = fmaxf(u0.w + v0.w + bb0.w, 0.f);
        float s4 = fmaxf(u1.x + v1.x + bb1.x, 0.f);
        float s5 = fmaxf(u1.y + v1.y + bb1.y, 0.f);
        float s6 = fmaxf(u1.z + v1.z + bb1.z, 0.f);
        float s7 = fmaxf(u1.w + v1.w + bb1.w, 0.f);
        split2(s0, s1, ah[m].u[0], al[m].u[0]);
        split2(s2, s3, ah[m].u[1], al[m].u[1]);
        split2(s4, s5, ah[m].u[2], al[m].u[2]);
        split2(s6, s7, ah[m].u[3], al[m].u[3]);
      }
#pragma unroll
      for (int ct = 0; ct < 8; ++ct) {
        int bidx = (kt * 4 + ks) * 128 + ct * 16 + fr;
        B8 bh, bl;
        bh.q = Blds[bidx];
        bl.q = Blds[bidx + 2048];
#pragma unroll
        for (int m = 0; m < 2; ++m) {
          acc[m][ct] = __builtin_amdgcn_mfma_f32_16x16x32_bf16(ah[m].v, bh.v, acc[m][ct], 0, 0, 0);
          acc[m][ct] = __builtin_amdgcn_mfma_f32_16x16x32_bf16(ah[m].v, bl.v, acc[m][ct], 0, 0, 0);
          acc[m][ct] = __builtin_amdgcn_mfma_f32_16x16x32_bf16(al[m].v, bh.v, acc[m][ct], 0, 0, 0);
        }
      }
    }
    // epilogue: lane's 8 consecutive edges = (m,r) regs; run-length max, relu-first atomicMax
    const int ebase = eb + ks * 8;
    int prev = -1;
    float runv[8];
#pragma unroll
    for (int j = 0; j < 8; ++j) {
      int e = ebase + j;
      if (e < E) {
        int d = csr_dst[e];
        const int m = j >> 2, r = j & 3;
        if (d != prev) {
          if (prev >= 0) {
#pragma unroll
            for (int ct = 0; ct < 8; ++ct)
              atomicMax(&agg[(size_t)prev * 128 + ct * 16 + fr], __float_as_uint(runv[ct]));
          }
          prev = d;
#pragma unroll
          for (int ct = 0; ct < 8; ++ct) runv[ct] = fmaxf(acc[m][ct][r] + b2[ct], 0.f);
        } else {
#pragma unroll
          for (int ct = 0; ct < 8; ++ct)
            runv[ct] = fmaxf(runv[ct], fmaxf(acc[m][ct][r] + b2[ct], 0.f));
        }
      }
    }
    if (prev >= 0) {
#pragma unroll
      for (int ct = 0; ct < 8; ++ct)
        atomicMax(&agg[(size_t)prev * 128 + ct * 16 + fr], __float_as_uint(runv[ct]));
    }
  }
}

// ---------- graph boundaries (batch is sorted) ----------
__global__ void gbound_k(const int* __restrict__ batch, int* __restrict__ gstart, int N) {
  int g = threadIdx.x;
  if (g > NGRAPHS) return;
  if (g == NGRAPHS) { gstart[NGRAPHS] = N; return; }
  int lo = 0, hi = N;
  while (lo < hi) {
    int mid = (lo + hi) >> 1;
    if (batch[mid] < g) lo = mid + 1; else hi = mid;
  }
  gstart[g] = lo;
}

// ---------- segmented pooling: grid = NGRAPHS*8, one atomic pair per (block,channel) ----------
__global__ __launch_bounds__(256) void pool_seg_k(const float* __restrict__ x,
                                                  const int* __restrict__ gstart,
                                                  unsigned* __restrict__ gmax,
                                                  float* __restrict__ gsum) {
  int g = blockIdx.x >> 3, s = blockIdx.x & 7;
  int lb = gstart[g], ub = gstart[g + 1];
  long len = ub - lb;
  int i0 = lb + (int)((len * s) >> 3);
  int i1 = lb + (int)((len * (s + 1)) >> 3);
  int c = threadIdx.x & 127, h = threadIdx.x >> 7;
  float m = 0.f, sm = 0.f;
  for (int i = i0 + h; i < i1; i += 2) {
    float v = x[(size_t)i * 128 + c];
    m = fmaxf(m, v);
    sm += v;
  }
  if (i1 > i0) {
    atomicMax(&gmax[g * 128 + c], __float_as_uint(m));
    atomicAdd(&gsum[g * 128 + c], sm);
  }
}

__global__ void g0_k(const unsigned* __restrict__ gmax, const float* __restrict__ gsum,
                     const int* __restrict__ gstart, float* __restrict__ g0) {
  int t = blockIdx.x * blockDim.x + threadIdx.x;  // 64*256
  int g = t >> 8, c = t & 255;
  float o;
  if (c < 128) o = __uint_as_float(gmax[g * 128 + c]);
  else {
    float cnt = (float)(gstart[g + 1] - gstart[g]);
    o = gsum[g * 128 + (c - 128)] / fmaxf(cnt, 1.f);
  }
  g0[t] = o;
}

// ---------- head FC (relu) ----------
__global__ __launch_bounds__(256) void fc_k(const float* __restrict__ X,
                                            const float* __restrict__ W,
                                            const float* __restrict__ b,
                                            float* __restrict__ Y, int K, int N) {
  __shared__ float xs[256];
  int g = blockIdx.x, c = threadIdx.x;
  for (int k = c; k < K; k += blockDim.x) xs[k] = X[g * K + k];
  __syncthreads();
  float acc = b[c];
  for (int k = 0; k < K; k++) acc = fmaf(xs[k], W[(size_t)k * N + c], acc);
  Y[g * N + c] = fmaxf(acc, 0.f);
}

// ---------- launch ----------
extern "C" void kernel_launch(void* const* d_in, const int* in_sizes, int n_in,
                              void* d_out, int out_size, void* d_ws, size_t ws_size,
                              hipStream_t stream) {
  const float* nodes = (const float*)d_in[0];
  const int* cats = (const int*)d_in[1];
  const int* eidx = (const int*)d_in[2];
  const int* batch = (const int*)d_in[3];
  const float* emb = (const float*)d_in[4];
  const float* W1 = (const float*)d_in[5];
  const float* b1 = (const float*)d_in[6];
  const float* W2 = (const float*)d_in[7];
  const float* b2 = (const float*)d_in[8];
  const float* W3 = (const float*)d_in[9];
  const float* b3 = (const float*)d_in[10];
  const float* We1 = (const float*)d_in[11];
  const float* be1 = (const float*)d_in[12];
  const float* We2 = (const float*)d_in[13];
  const float* be2 = (const float*)d_in[14];
  const float* Wf1 = (const float*)d_in[15];
  const float* bf1 = (const float*)d_in[16];
  const float* Wf2 = (const float*)d_in[17];
  const float* bf2 = (const float*)d_in[18];
  float* out = (float*)d_out;

  const int N = in_sizes[0] / FEAT;
  const int E = in_sizes[2] / 2;
  const int Npad = ((N + 127) / 128) * 128;
  const int* src = eidx;
  const int* dst = eidx + E;

  char* w = (char*)d_ws;
  auto alloc = [&](size_t bytes) -> void* {
    void* p = (void*)w;
    w += (bytes + 255) & ~(size_t)255;
    return p;
  };
  unsigned* xh = (unsigned*)alloc((size_t)Npad * 32 * 4);   // [Npad x 64] bf16 pairs
  unsigned* xl = (unsigned*)alloc((size_t)Npad * 32 * 4);
  unsigned* ahb = (unsigned*)alloc((size_t)Npad * 64 * 4);  // [Npad x 128] bf16 pairs
  unsigned* alb = (unsigned*)alloc((size_t)Npad * 64 * 4);
  float* bufF = (float*)alloc((size_t)Npad * 128 * 4);      // gemm out / U
  float* bufV = (float*)alloc((size_t)Npad * 128 * 4);
  unsigned* agg = (unsigned*)alloc((size_t)N * 128 * 4);
  int* indeg = (int*)alloc((size_t)N * 4);
  int* rowst = (int*)alloc((size_t)(N + 1) * 4);
  int* cursor = (int*)alloc((size_t)N * 4);
  float* dinv = (float*)alloc((size_t)N * 4);
  int* csr_src = (int*)alloc((size_t)E * 4);
  int* csr_dst = (int*)alloc((size_t)E * 4);
  float* csr_norm = (float*)alloc((size_t)E * 4);
  unsigned short* W1p = (unsigned short*)alloc(2 * 64 * 128 * 2);
  unsigned short* W2p = (unsigned short*)alloc(2 * 128 * 128 * 2);
  unsigned short* W3p = (unsigned short*)alloc(2 * 128 * 128 * 2);
  unsigned short* Wdp = (unsigned short*)alloc(2 * 128 * 128 * 2);
  unsigned short* Wvp = (unsigned short*)alloc(2 * 128 * 128 * 2);
  unsigned short* We2p = (unsigned short*)alloc(2 * 128 * 128 * 2);
  float* g0buf = (float*)alloc(NGRAPHS * 256 * 4);
  float* g1buf = (float*)alloc(NGRAPHS * 256 * 4);
  unsigned* gmax = (unsigned*)alloc(NGRAPHS * 128 * 4);
  float* gsum = (float*)alloc(NGRAPHS * 128 * 4);
  int* gstart = (int*)alloc((NGRAPHS + 1) * 4);
  if ((size_t)(w - (char*)d_ws) > ws_size) return;

  hipMemsetAsync(indeg, 0, (size_t)N * 4, stream);
  hipMemsetAsync(agg, 0, (size_t)N * 128 * 4, stream);
  hipMemsetAsync(gmax, 0, NGRAPHS * 128 * 4, stream);
  hipMemsetAsync(gsum, 0, NGRAPHS * 128 * 4, stream);

  const int TB = 256;
  int gE = (E + TB - 1) / TB;
  int gN = (N + TB - 1) / TB;

  hist_k<<<gE, TB, 0, stream>>>(dst, indeg, E);
  dinv_k<<<gN, TB, 0, stream>>>(indeg, dinv, N);
  scan_k<<<1, 1024, 0, stream>>>(indeg, rowst, cursor, N);
  fill_k<<<gE, TB, 0, stream>>>(src, dst, dinv, cursor, csr_src, csr_dst, csr_norm, E);
  gbound_k<<<1, 128, 0, stream>>>(batch, gstart, N);

  xcat_split_k<<<(N * 32 + TB - 1) / TB, TB, 0, stream>>>(nodes, cats, emb, xh, xl, N);

  pack_k<<<32, TB, 0, stream>>>(W1, nullptr, W1p, 64);
  pack_k<<<64, TB, 0, stream>>>(W2, nullptr, W2p, 128);
  pack_k<<<64, TB, 0, stream>>>(W3, nullptr, W3p, 128);
  pack_k<<<64, TB, 0, stream>>>(We1, We1 + 128 * 128, Wdp, 128);  // top - bot
  pack_k<<<64, TB, 0, stream>>>(We1 + 128 * 128, nullptr, Wvp, 128);
  pack_k<<<64, TB, 0, stream>>>(We2, nullptr, We2p, 128);

  const int gemmGrid = Npad / 128;
  const int waveGrid = (N * 64 + TB - 1) / TB;

  gemm_mfma<<<gemmGrid, TB, 0, stream>>>((unsigned short*)xh, (unsigned short*)xl, W1p, bufF, N, 64);
  gcn_agg_split_k<<<waveGrid, TB, 0, stream>>>(bufF, csr_src, csr_norm, rowst, dinv, b1, ahb, alb, N);
  gemm_mfma<<<gemmGrid, TB, 0, stream>>>((unsigned short*)ahb, (unsigned short*)alb, W2p, bufF, N, 128);
  gcn_agg_split_k<<<waveGrid, TB, 0, stream>>>(bufF, csr_src, csr_norm, rowst, dinv, b2, ahb, alb, N);
  gemm_mfma<<<gemmGrid, TB, 0, stream>>>((unsigned short*)ahb, (unsigned short*)alb, W3p, bufF, N, 128);
  gcn_agg_split_k<<<waveGrid, TB, 0, stream>>>(bufF, csr_src, csr_norm, rowst, dinv, b3, ahb, alb, N);

  // EdgeConv precompute: U = x3 @ (We1_top - We1_bot) -> bufF ; V = x3 @ We1_bot -> bufV
  gemm_mfma<<<gemmGrid, TB, 0, stream>>>((unsigned short*)ahb, (unsigned short*)alb, Wdp, bufF, N, 128);
  gemm_mfma<<<gemmGrid, TB, 0, stream>>>((unsigned short*)ahb, (unsigned short*)alb, Wvp, bufV, N, 128);

  const int ntiles = (E + 127) / 128;
  edgeconv_mfma<<<2048, TB, 0, stream>>>(bufF, bufV, csr_src, csr_dst, be1, We2p, be2, agg, E, ntiles);

  pool_seg_k<<<NGRAPHS * 8, TB, 0, stream>>>((const float*)agg, gstart, gmax, gsum);
  g0_k<<<NGRAPHS, TB, 0, stream>>>(gmax, gsum, gstart, g0buf);
  fc_k<<<NGRAPHS, 256, 0, stream>>>(g0buf, Wf1, bf1, g1buf, 256, 256);
  fc_k<<<NGRAPHS, 256, 0, stream>>>(g1buf, Wf2, bf2, out, 256, 256);
}